// Round 7
// baseline (333.673 us; speedup 1.0000x reference)
//
#include <hip/hip_runtime.h>
#include <stdint.h>

#define HIDDEN 1024
#define HEADS 16
#define HEAD_DIM 64
#define BATCH 4
#define SEQ 2048
#define ROWS (BATCH * SEQ) /* 8192 */

typedef float f32x4 __attribute__((ext_vector_type(4)));
typedef short bf16x8 __attribute__((ext_vector_type(8))); // 8 bf16 = 4 VGPRs

__device__ __forceinline__ uint16_t f32_to_bf16_rne(float f) {
    uint32_t u = __float_as_uint(f);
    uint32_t r = u + 0x7FFFu + ((u >> 16) & 1u);
    return (uint16_t)(r >> 16);
}
__device__ __forceinline__ float bf16_to_f32(uint16_t u) {
    return __uint_as_float(((uint32_t)u) << 16);
}

// ---------------------------------------------------------------------------
// Kernel 0: Xq fp32 -> bf16 (row-major), ILP x4.
// ---------------------------------------------------------------------------
__global__ __launch_bounds__(256) void cvt_q(const float* __restrict__ Xq,
                                             uint16_t* __restrict__ XqB) {
    size_t base = (size_t)blockIdx.x * 1024 + threadIdx.x; // float4 idx
    const float4* Xi = (const float4*)Xq;
    float4 f0 = Xi[base];
    float4 f1 = Xi[base + 256];
    float4 f2 = Xi[base + 512];
    float4 f3 = Xi[base + 768];
    uint2* Oi = (uint2*)XqB;
    uint2 p;
    p.x = (uint32_t)f32_to_bf16_rne(f0.x) | ((uint32_t)f32_to_bf16_rne(f0.y) << 16);
    p.y = (uint32_t)f32_to_bf16_rne(f0.z) | ((uint32_t)f32_to_bf16_rne(f0.w) << 16);
    Oi[base] = p;
    p.x = (uint32_t)f32_to_bf16_rne(f1.x) | ((uint32_t)f32_to_bf16_rne(f1.y) << 16);
    p.y = (uint32_t)f32_to_bf16_rne(f1.z) | ((uint32_t)f32_to_bf16_rne(f1.w) << 16);
    Oi[base + 256] = p;
    p.x = (uint32_t)f32_to_bf16_rne(f2.x) | ((uint32_t)f32_to_bf16_rne(f2.y) << 16);
    p.y = (uint32_t)f32_to_bf16_rne(f2.z) | ((uint32_t)f32_to_bf16_rne(f2.w) << 16);
    Oi[base + 512] = p;
    p.x = (uint32_t)f32_to_bf16_rne(f3.x) | ((uint32_t)f32_to_bf16_rne(f3.y) << 16);
    p.y = (uint32_t)f32_to_bf16_rne(f3.z) | ((uint32_t)f32_to_bf16_rne(f3.w) << 16);
    Oi[base + 768] = p;
}

// ---------------------------------------------------------------------------
// Kernel 1: per-batch transpose Xk,Xv fp32 -> XkT,XvT bf16 [b][1024 i][2048 s]
//   + per-batch column sums rk[b][i], rv[b][i] (atomic, buffers pre-zeroed).
//   grid (32 s-tiles, 16 i-tiles, z*4+b), block 256. wt_kernel pattern.
// ---------------------------------------------------------------------------
__global__ __launch_bounds__(256) void cvt_t(const float* __restrict__ Xk,
                                             const float* __restrict__ Xv,
                                             uint16_t* __restrict__ XkT,
                                             uint16_t* __restrict__ XvT,
                                             float* __restrict__ rk,
                                             float* __restrict__ rv) {
    const int z = blockIdx.z >> 2, b = blockIdx.z & 3;
    const float* X = z ? Xv : Xk;
    uint16_t* XT = z ? XvT : XkT;
    float* rsum = z ? rv : rk;
    __shared__ float tile[64][65];
    const int s0 = blockIdx.x * 64, i0 = blockIdx.y * 64;
    const int r = threadIdx.x >> 6, c = threadIdx.x & 63;
    for (int it = 0; it < 16; ++it) {
        int rr = r + 4 * it;
        tile[rr][c] = X[(size_t)(b * SEQ + s0 + rr) * HIDDEN + i0 + c];
    }
    __syncthreads();
    for (int it = 0; it < 16; ++it) {
        int rr = r + 4 * it;
        XT[(size_t)b * (HIDDEN * SEQ) + (size_t)(i0 + rr) * SEQ + s0 + c] =
            f32_to_bf16_rne(tile[c][rr]);
    }
    if (threadIdx.x < 64) {
        float s = 0.f;
        for (int row = 0; row < 64; ++row) s += tile[row][threadIdx.x];
        atomicAdd(&rsum[b * HIDDEN + i0 + threadIdx.x], s);
    }
}

// ---------------------------------------------------------------------------
// Kernel 2: W[K][N] fp32 -> Wt[N][K] bf16, z in {Wk, Wv}
// ---------------------------------------------------------------------------
__global__ __launch_bounds__(256) void wt_kernel(const float* __restrict__ Wk,
                                                 const float* __restrict__ Wv,
                                                 uint16_t* __restrict__ Wt) {
    const float* W = blockIdx.z == 0 ? Wk : Wv;
    uint16_t* out = Wt + (size_t)blockIdx.z * HIDDEN * HIDDEN;
    __shared__ float tile[64][65];
    int k0 = blockIdx.x * 64, n0 = blockIdx.y * 64;
    int r = threadIdx.x >> 6, c = threadIdx.x & 63;
    for (int it = 0; it < 16; ++it) {
        int rr = r + 4 * it;
        tile[rr][c] = W[(size_t)(k0 + rr) * HIDDEN + n0 + c];
    }
    __syncthreads();
    for (int it = 0; it < 16; ++it) {
        int rr = r + 4 * it;
        out[(size_t)(n0 + rr) * HIDDEN + k0 + c] = f32_to_bf16_rne(tile[c][rr]);
    }
}

// ---------------------------------------------------------------------------
// Kernel 3: generic batched m97 GEMM  C[m][n] = sum_k A[m][k]*B[n][k].
//   Verified 128x128 structure, runtime K, per-batch strides (elements).
//   BF16OUT selects bf16 vs fp32 C. N fixed at 1024 (all uses).
// ---------------------------------------------------------------------------
template <bool BF16OUT>
__global__ __launch_bounds__(256) void gemm_bt(const uint16_t* __restrict__ A,
                                               const uint16_t* __restrict__ B,
                                               void* __restrict__ Cv, int K,
                                               size_t sA, size_t sB, size_t sC) {
    const int b = blockIdx.z;
    const uint16_t* Ab = A + sA * b;
    const uint16_t* Bb = B + sB * b;

    __shared__ uint16_t slds[16384]; // A: [0,8192), B: [8192,16384)

    const int tid = threadIdx.x;
    const int lane = tid & 63;
    const int w = tid >> 6;
    const int wm = (w >> 1) * 64;
    const int wn = (w & 1) * 64;
    const int m_lane = lane & 15;
    const int kq = lane >> 4;
    const int m0 = blockIdx.x * 128;
    const int n0 = blockIdx.y * 128;

    f32x4 acc[4][4] = {};

    for (int kb = 0; kb < K; kb += 64) {
        for (int t = 0; t < 4; ++t) {
            int gbase = (w * 4 + t) * 64;
            int g = gbase + lane;
            int r = g >> 3;
            int c = (g & 7) ^ (r & 7);
            const uint16_t* srcA = Ab + (size_t)(m0 + r) * K + kb + c * 8;
            __builtin_amdgcn_global_load_lds(
                (const __attribute__((address_space(1))) uint32_t*)srcA,
                (__attribute__((address_space(3))) uint32_t*)(&slds[gbase * 8]),
                16, 0, 0);
            const uint16_t* srcB = Bb + (size_t)(n0 + r) * K + kb + c * 8;
            __builtin_amdgcn_global_load_lds(
                (const __attribute__((address_space(1))) uint32_t*)srcB,
                (__attribute__((address_space(3))) uint32_t*)(&slds[8192 + gbase * 8]),
                16, 0, 0);
        }
        __syncthreads();
        for (int ks = 0; ks < 2; ++ks) {
            int cbase = ks * 4 + kq;
            bf16x8 af[4], bfr[4];
            for (int i = 0; i < 4; ++i) {
                int r = wm + i * 16 + m_lane;
                int p = cbase ^ (r & 7);
                af[i] = *(const bf16x8*)(&slds[r * 64 + p * 8]);
            }
            for (int j = 0; j < 4; ++j) {
                int nr = wn + j * 16 + m_lane;
                int p = cbase ^ (nr & 7);
                bfr[j] = *(const bf16x8*)(&slds[8192 + nr * 64 + p * 8]);
            }
            for (int i = 0; i < 4; ++i)
                for (int j = 0; j < 4; ++j)
                    acc[i][j] = __builtin_amdgcn_mfma_f32_16x16x32_bf16(
                        af[i], bfr[j], acc[i][j], 0, 0, 0);
        }
        __syncthreads();
    }

    for (int j = 0; j < 4; ++j) {
        int col = n0 + wn + j * 16 + m_lane;
        for (int i = 0; i < 4; ++i) {
            int rbase = m0 + wm + i * 16 + kq * 4;
            for (int rg = 0; rg < 4; ++rg) {
                float v = acc[i][j][rg];
                size_t idx = sC * b + (size_t)(rbase + rg) * 1024 + col;
                if (BF16OUT)
                    ((uint16_t*)Cv)[idx] = f32_to_bf16_rne(v);
                else
                    ((float*)Cv)[idx] = v;
            }
        }
    }
}

// ---------------------------------------------------------------------------
// Kernel 4: kq[b][n] = sum_i Wkt[n][i]*rk[b][i];  vvv[b][n] = Wvt row . rv[b].
// grid (4 nchunks, 4 b), block 256, one row per thread.
// ---------------------------------------------------------------------------
__global__ __launch_bounds__(256) void kvq_kernel(const uint16_t* __restrict__ Wkt,
                                                  const uint16_t* __restrict__ Wvt,
                                                  const float* __restrict__ rk,
                                                  const float* __restrict__ rv,
                                                  float* __restrict__ kq,
                                                  float* __restrict__ vvv) {
    const int b = blockIdx.y;
    const int n = blockIdx.x * 256 + threadIdx.x;
    float s1 = 0.f, s2 = 0.f;
    for (int i = 0; i < HIDDEN; i += 8) {
        bf16x8 wk8 = *(const bf16x8*)(Wkt + (size_t)n * HIDDEN + i);
        bf16x8 wv8 = *(const bf16x8*)(Wvt + (size_t)n * HIDDEN + i);
        for (int e = 0; e < 8; ++e) {
            s1 += bf16_to_f32((uint16_t)wk8[e]) * rk[b * HIDDEN + i + e];
            s2 += bf16_to_f32((uint16_t)wv8[e]) * rv[b * HIDDEN + i + e];
        }
    }
    kq[b * HIDDEN + n] = s1;
    vvv[b * HIDDEN + n] = s2;
}

// ---------------------------------------------------------------------------
// Kernel 5: M partials. P[bh][jc][p][q] = 0.125*( sum_{j in jc-chunk}
//   T[b][h*64+p][j]*Wvt[h*64+q][j]  (+ bias rank-1 terms, jc==0 only) ).
//   grid (16 h, 4 b, 4 jc), block 256. kv_kernel inner structure.
// ---------------------------------------------------------------------------
__global__ __launch_bounds__(256) void m_kernel(const float* __restrict__ T32,
                                                const uint16_t* __restrict__ Wvt,
                                                const float* __restrict__ kq,
                                                const float* __restrict__ vvv,
                                                const float* __restrict__ Bk,
                                                const float* __restrict__ Bv,
                                                float* __restrict__ P) {
    const int h = blockIdx.x, b = blockIdx.y, jc = blockIdx.z;
    const int tid = threadIdx.x;
    __shared__ float tt[16][64];
    __shared__ float vl[16][64];
    float acc[4][4] = {};
    const int p0 = (tid >> 4) * 4, q0 = (tid & 15) * 4;
    const int jbase = jc * 256;

    for (int jb = 0; jb < 16; ++jb) {
        __syncthreads();
        if (tid < 128) {
            int p = tid >> 1, half = tid & 1;
            const float* src = T32 + (size_t)b * (HIDDEN * HIDDEN) +
                               (size_t)(h * 64 + p) * HIDDEN + jbase + jb * 16 + half * 8;
            float4 d0 = *(const float4*)src;
            float4 d1 = *(const float4*)(src + 4);
            tt[half * 8 + 0][p] = d0.x; tt[half * 8 + 1][p] = d0.y;
            tt[half * 8 + 2][p] = d0.z; tt[half * 8 + 3][p] = d0.w;
            tt[half * 8 + 4][p] = d1.x; tt[half * 8 + 5][p] = d1.y;
            tt[half * 8 + 6][p] = d1.z; tt[half * 8 + 7][p] = d1.w;
        } else {
            int t2 = tid - 128;
            int q = t2 >> 1, half = t2 & 1;
            bf16x8 d = *(const bf16x8*)(Wvt + (size_t)(h * 64 + q) * HIDDEN +
                                        jbase + jb * 16 + half * 8);
            for (int e = 0; e < 8; ++e) vl[half * 8 + e][q] = bf16_to_f32((uint16_t)d[e]);
        }
        __syncthreads();
        for (int r = 0; r < 16; ++r) {
            f32x4 ka = *(const f32x4*)(&tt[r][p0]);
            f32x4 va = *(const f32x4*)(&vl[r][q0]);
            for (int a = 0; a < 4; ++a)
                for (int bb = 0; bb < 4; ++bb)
                    acc[a][bb] += ka[a] * va[bb];
        }
    }

    float* Pp = P + ((size_t)(b * 16 + h) * 4 + jc) * 4096;
    for (int a = 0; a < 4; ++a) {
        f32x4 row;
        for (int bb = 0; bb < 4; ++bb) {
            float v = acc[a][bb];
            if (jc == 0) {
                int hp = h * 64 + p0 + a, hq = h * 64 + q0 + bb;
                v += Bk[hp] * vvv[b * HIDDEN + hq] + kq[b * HIDDEN + hp] * Bv[hq] +
                     2048.0f * Bk[hp] * Bv[hq];
            }
            row[bb] = v * 0.125f;
        }
        *(f32x4*)(&Pp[(p0 + a) * 64 + q0]) = row;
    }
}

// ---------------------------------------------------------------------------
// Kernel 6: fold M into weights — PER BATCH. Sums the 4 jc partials inline.
// ---------------------------------------------------------------------------
__global__ __launch_bounds__(256) void wprime_kernel(const float* __restrict__ Wq,
                                                     const float* __restrict__ bq,
                                                     const float* __restrict__ P,
                                                     uint16_t* __restrict__ Wpt,
                                                     float* __restrict__ bp) {
    const int h = blockIdx.x;
    const int r0 = blockIdx.y * 64;
    const int b = blockIdx.z;
    const int tid = threadIdx.x;

    __shared__ float Mh[64][65];
    __shared__ float Wl[64][65];
    const float* Pp = P + (size_t)(b * 16 + h) * 4 * 4096;
    for (int it = 0; it < 16; ++it) {
        int e = it * 256 + tid;
        int a = e >> 6, c = e & 63;
        float s = 0.f;
        for (int sc = 0; sc < 4; ++sc) s += Pp[sc * 4096 + e];
        Mh[a][c] = s;
        Wl[a][c] = Wq[(size_t)(r0 + a) * HIDDEN + h * 64 + c];
    }
    __syncthreads();

    const int r = tid & 63;
    const int jbase = tid >> 6; // 0..3
    float acc[16] = {};
    for (int i = 0; i < 64; ++i) {
        float wv = Wl[r][i];
        for (int jj = 0; jj < 16; ++jj)
            acc[jj] += wv * Mh[i][jbase + 4 * jj];
    }
    uint16_t* Wb = Wpt + (size_t)b * HIDDEN * HIDDEN;
    for (int jj = 0; jj < 16; ++jj) {
        int n = h * 64 + jbase + 4 * jj;
        Wb[(size_t)n * HIDDEN + r0 + r] = f32_to_bf16_rne(acc[jj]);
    }

    if (blockIdx.y == 0 && tid < 64) {
        int j = tid;
        float s = 0.f;
        for (int i = 0; i < 64; ++i) s += bq[h * 64 + i] * Mh[i][j];
        bp[b * HIDDEN + h * 64 + j] = s;
    }
}

// ---------------------------------------------------------------------------
// Kernel 7: out = Xq @ W'_b^T + b'_b   (fp32 output to d_out)
// ---------------------------------------------------------------------------
__global__ __launch_bounds__(256) void final_gemm(const uint16_t* __restrict__ Xq,
                                                  const uint16_t* __restrict__ Wpt,
                                                  const float* __restrict__ bp,
                                                  float* __restrict__ out) {
    __shared__ uint16_t slds[16384];

    const int tid = threadIdx.x;
    const int lane = tid & 63;
    const int w = tid >> 6;
    const int wm = (w >> 1) * 64;
    const int wn = (w & 1) * 64;
    const int m_lane = lane & 15;
    const int kq = lane >> 4;
    const int m0 = blockIdx.x * 128;
    const int n0 = blockIdx.y * 128;
    const int batch = m0 >> 11;
    const uint16_t* W = Wpt + (size_t)batch * HIDDEN * HIDDEN;
    const float* bias = bp + batch * HIDDEN;

    f32x4 acc[4][4] = {};

    for (int kb = 0; kb < HIDDEN; kb += 64) {
        for (int t = 0; t < 4; ++t) {
            int gbase = (w * 4 + t) * 64;
            int g = gbase + lane;
            int r = g >> 3;
            int c = (g & 7) ^ (r & 7);
            const uint16_t* srcA = Xq + (size_t)(m0 + r) * HIDDEN + kb + c * 8;
            __builtin_amdgcn_global_load_lds(
                (const __attribute__((address_space(1))) uint32_t*)srcA,
                (__attribute__((address_space(3))) uint32_t*)(&slds[gbase * 8]),
                16, 0, 0);
            const uint16_t* srcB = W + (size_t)(n0 + r) * HIDDEN + kb + c * 8;
            __builtin_amdgcn_global_load_lds(
                (const __attribute__((address_space(1))) uint32_t*)srcB,
                (__attribute__((address_space(3))) uint32_t*)(&slds[8192 + gbase * 8]),
                16, 0, 0);
        }
        __syncthreads();
        for (int ks = 0; ks < 2; ++ks) {
            int cbase = ks * 4 + kq;
            bf16x8 af[4], bfr[4];
            for (int i = 0; i < 4; ++i) {
                int r = wm + i * 16 + m_lane;
                int p = cbase ^ (r & 7);
                af[i] = *(const bf16x8*)(&slds[r * 64 + p * 8]);
            }
            for (int j = 0; j < 4; ++j) {
                int nr = wn + j * 16 + m_lane;
                int p = cbase ^ (nr & 7);
                bfr[j] = *(const bf16x8*)(&slds[8192 + nr * 64 + p * 8]);
            }
            for (int i = 0; i < 4; ++i)
                for (int j = 0; j < 4; ++j)
                    acc[i][j] = __builtin_amdgcn_mfma_f32_16x16x32_bf16(
                        af[i], bfr[j], acc[i][j], 0, 0, 0);
        }
        __syncthreads();
    }

    for (int j = 0; j < 4; ++j) {
        int col = n0 + wn + j * 16 + m_lane;
        float bj = bias[col];
        for (int i = 0; i < 4; ++i) {
            int rbase = m0 + wm + i * 16 + kq * 4;
            for (int rg = 0; rg < 4; ++rg)
                out[(size_t)(rbase + rg) * HIDDEN + col] = acc[i][j][rg] + bj;
        }
    }
}

// ---------------------------------------------------------------------------
extern "C" void kernel_launch(void* const* d_in, const int* in_sizes, int n_in,
                              void* d_out, int out_size, void* d_ws, size_t ws_size,
                              hipStream_t stream) {
    const float* Xq = (const float*)d_in[0];
    const float* Xk = (const float*)d_in[1];
    const float* Xv = (const float*)d_in[2];
    const float* Wq = (const float*)d_in[3];
    const float* Bq = (const float*)d_in[4];
    const float* Wk = (const float*)d_in[5];
    const float* Bk = (const float*)d_in[6];
    const float* Wv = (const float*)d_in[7];
    const float* Bv = (const float*)d_in[8];
    float* out = (float*)d_out;

    char* ws = (char*)d_ws;
    uint16_t* XqB = (uint16_t*)ws;                  // 16,777,216 B
    uint16_t* XkT = (uint16_t*)(ws + 16777216);     // 16,777,216 B [b][i][s]
    uint16_t* XvT = (uint16_t*)(ws + 33554432);     // 16,777,216 B
    uint16_t* Wt = (uint16_t*)(ws + 50331648);      //  4,194,304 B (Wkt, Wvt)
    uint16_t* Gt = (uint16_t*)(ws + 54525952);      //  8,388,608 B [b][j][i] bf16
    float* T32 = (float*)(ws + 62914560);           // 16,777,216 B [b][n][j] fp32
    float* P = (float*)(ws + 79691776);             //  4,194,304 B [bh][4jc][4096]
    uint16_t* Wpt = (uint16_t*)(ws + 83886080);     //  8,388,608 B
    float* bp = (float*)(ws + 92274688);            //     16,384 B
    float* rk = (float*)(ws + 92291072);            //     16,384 B
    float* rv = (float*)(ws + 92307456);            //     16,384 B
    float* kq = (float*)(ws + 92323840);            //     16,384 B
    float* vvv = (float*)(ws + 92340224);           //     16,384 B  (~92.4 MB)

    const uint16_t* Wkt = Wt;
    const uint16_t* Wvt = Wt + (size_t)HIDDEN * HIDDEN;

    // zero the colsum accumulators (rk, rv)
    hipMemsetAsync(ws + 92291072, 0, 32768, stream);

    cvt_q<<<dim3(2048), 256, 0, stream>>>(Xq, XqB);
    cvt_t<<<dim3(32, 16, 8), 256, 0, stream>>>(Xk, Xv, XkT, XvT, rk, rv);
    wt_kernel<<<dim3(16, 16, 2), 256, 0, stream>>>(Wk, Wv, Wt);

    // Gt[b][j][i] = sum_s XvT[b][j][s] * XkT[b][i][s]   (= G_b[i][j] transposed)
    gemm_bt<true><<<dim3(8, 8, 4), 256, 0, stream>>>(
        XvT, XkT, Gt, 2048, (size_t)HIDDEN * SEQ, (size_t)HIDDEN * SEQ,
        (size_t)HIDDEN * HIDDEN);
    // T[b][n][j] = sum_i Wkt[n][i] * Gt[b][j][i]   (= (Wk^T G_b)[n][j], fp32)
    gemm_bt<false><<<dim3(8, 8, 4), 256, 0, stream>>>(
        Wkt, Gt, T32, 1024, 0, (size_t)HIDDEN * HIDDEN, (size_t)HIDDEN * HIDDEN);

    kvq_kernel<<<dim3(4, 4), 256, 0, stream>>>(Wkt, Wvt, rk, rv, kq, vvv);
    m_kernel<<<dim3(16, 4, 4), 256, 0, stream>>>(T32, Wvt, kq, vvv, Bk, Bv, P);
    wprime_kernel<<<dim3(16, 16, 4), 256, 0, stream>>>(Wq, Bq, P, Wpt, bp);
    final_gemm<<<dim3(64, 8), 256, 0, stream>>>(XqB, Wpt, bp, out);
}

// Round 8
// 269.864 us; speedup vs baseline: 1.2364x; 1.2364x over previous
//
#include <hip/hip_runtime.h>
#include <stdint.h>

#define HIDDEN 1024
#define HEADS 16
#define HEAD_DIM 64
#define BATCH 4
#define SEQ 2048
#define ROWS (BATCH * SEQ) /* 8192 */

typedef float f32x4 __attribute__((ext_vector_type(4)));
typedef short bf16x8 __attribute__((ext_vector_type(8))); // 8 bf16 = 4 VGPRs

__device__ __forceinline__ uint16_t f32_to_bf16_rne(float f) {
    uint32_t u = __float_as_uint(f);
    uint32_t r = u + 0x7FFFu + ((u >> 16) & 1u);
    return (uint16_t)(r >> 16);
}
__device__ __forceinline__ float bf16_to_f32(uint16_t u) {
    return __uint_as_float(((uint32_t)u) << 16);
}

// ---------------------------------------------------------------------------
// Kernel 0: convert X (q,k,v inputs) fp32 -> bf16, fully coalesced.
//   (Best-measured variant: R4 bench 269.6 total; 41.7 us standalone.)
// ---------------------------------------------------------------------------
__global__ __launch_bounds__(256) void cvt_kernel(const float* __restrict__ Xq,
                                                  const float* __restrict__ Xk,
                                                  const float* __restrict__ Xv,
                                                  uint16_t* __restrict__ Xb) {
    int z = blockIdx.x >> 13; // 8192 blocks per array
    const float* X = z == 0 ? Xq : (z == 1 ? Xk : Xv);
    uint16_t* out = Xb + (size_t)z * ROWS * HIDDEN;
    size_t i4 = (size_t)(blockIdx.x & 8191) * 256 + threadIdx.x; // float4 index
    float4 f = ((const float4*)X)[i4];
    uint2 pk;
    pk.x = (uint32_t)f32_to_bf16_rne(f.x) | ((uint32_t)f32_to_bf16_rne(f.y) << 16);
    pk.y = (uint32_t)f32_to_bf16_rne(f.z) | ((uint32_t)f32_to_bf16_rne(f.w) << 16);
    ((uint2*)out)[i4] = pk;
}

// ---------------------------------------------------------------------------
// Kernel 1: W[K][N] fp32 -> Wt[N][K] bf16, z in {Wk, Wv} only (Wq stays fp32)
// ---------------------------------------------------------------------------
__global__ __launch_bounds__(256) void wt_kernel(const float* __restrict__ Wk,
                                                 const float* __restrict__ Wv,
                                                 uint16_t* __restrict__ Wt) {
    const float* W = blockIdx.z == 0 ? Wk : Wv;
    uint16_t* out = Wt + (size_t)blockIdx.z * HIDDEN * HIDDEN;
    __shared__ float tile[64][65];
    int k0 = blockIdx.x * 64, n0 = blockIdx.y * 64;
    int r = threadIdx.x >> 6, c = threadIdx.x & 63;
    for (int it = 0; it < 16; ++it) {
        int rr = r + 4 * it;
        tile[rr][c] = W[(size_t)(k0 + rr) * HIDDEN + n0 + c];
    }
    __syncthreads();
    for (int it = 0; it < 16; ++it) {
        int rr = r + 4 * it;
        out[(size_t)(n0 + rr) * HIDDEN + k0 + c] = f32_to_bf16_rne(tile[c][rr]);
    }
}

// ---------------------------------------------------------------------------
// Kernel 2: K/V projection GEMM  KV[z] = Xkv[z] @ Wt[z]^T + bias  (bf16 MFMA)
//   Round-0-verified m97 structure, 128x128 tile, both z in one launch.
//   (8-phase variants abandoned: 256^2 spills at 2 waves/SIMD (3 rounds);
//    non-spilling 256x128 measured parity in R5. Gram restructure measured
//    -61 us total in R7. This kernel is the session's verified floor.)
// ---------------------------------------------------------------------------
__global__ __launch_bounds__(256) void proj_gemm(const uint16_t* __restrict__ Xkv,
                                                 const uint16_t* __restrict__ Wt,
                                                 const float* __restrict__ Bk,
                                                 const float* __restrict__ Bv,
                                                 uint16_t* __restrict__ KV) {
    const int z = blockIdx.z; // 0=K, 1=V
    const uint16_t* X = Xkv + (size_t)z * ROWS * HIDDEN;
    const uint16_t* W = Wt + (size_t)z * HIDDEN * HIDDEN;
    const float* bias = z == 0 ? Bk : Bv;
    uint16_t* out = KV + (size_t)z * ROWS * HIDDEN;

    __shared__ uint16_t slds[16384]; // A: [0,8192), B: [8192,16384)

    const int tid = threadIdx.x;
    const int lane = tid & 63;
    const int w = tid >> 6;
    const int wm = (w >> 1) * 64;
    const int wn = (w & 1) * 64;
    const int m_lane = lane & 15;
    const int kq = lane >> 4;
    const int m0 = blockIdx.x * 128;
    const int n0 = blockIdx.y * 128;

    f32x4 acc[4][4] = {};

    for (int kb = 0; kb < HIDDEN; kb += 64) {
        for (int t = 0; t < 4; ++t) {
            int gbase = (w * 4 + t) * 64;
            int g = gbase + lane;
            int r = g >> 3;
            int c = (g & 7) ^ (r & 7);
            const uint16_t* srcA = X + (size_t)(m0 + r) * HIDDEN + kb + c * 8;
            __builtin_amdgcn_global_load_lds(
                (const __attribute__((address_space(1))) uint32_t*)srcA,
                (__attribute__((address_space(3))) uint32_t*)(&slds[gbase * 8]),
                16, 0, 0);
            const uint16_t* srcB = W + (size_t)(n0 + r) * HIDDEN + kb + c * 8;
            __builtin_amdgcn_global_load_lds(
                (const __attribute__((address_space(1))) uint32_t*)srcB,
                (__attribute__((address_space(3))) uint32_t*)(&slds[8192 + gbase * 8]),
                16, 0, 0);
        }
        __syncthreads();
        for (int ks = 0; ks < 2; ++ks) {
            int cbase = ks * 4 + kq;
            bf16x8 af[4], bfr[4];
            for (int i = 0; i < 4; ++i) {
                int r = wm + i * 16 + m_lane;
                int p = cbase ^ (r & 7);
                af[i] = *(const bf16x8*)(&slds[r * 64 + p * 8]);
            }
            for (int j = 0; j < 4; ++j) {
                int nr = wn + j * 16 + m_lane;
                int p = cbase ^ (nr & 7);
                bfr[j] = *(const bf16x8*)(&slds[8192 + nr * 64 + p * 8]);
            }
            for (int i = 0; i < 4; ++i)
                for (int j = 0; j < 4; ++j)
                    acc[i][j] = __builtin_amdgcn_mfma_f32_16x16x32_bf16(
                        af[i], bfr[j], acc[i][j], 0, 0, 0);
        }
        __syncthreads();
    }

    for (int j = 0; j < 4; ++j) {
        int col = n0 + wn + j * 16 + m_lane;
        float bj = bias[col];
        for (int i = 0; i < 4; ++i) {
            int rbase = m0 + wm + i * 16 + kq * 4;
            for (int rg = 0; rg < 4; ++rg) {
                float v = acc[i][j][rg] + bj;
                out[(size_t)(rbase + rg) * HIDDEN + col] = f32_to_bf16_rne(v);
            }
        }
    }
}

// ---------------------------------------------------------------------------
// Kernel 3: P[bh][sc] = (1/8) * K_h^T V_h over a 256-row S chunk.
//   NO atomics: each block owns a private 64x64 fp32 partial.
// ---------------------------------------------------------------------------
__global__ __launch_bounds__(256) void kv_kernel(const uint16_t* __restrict__ KV,
                                                 float* __restrict__ P) {
    const uint16_t* K = KV;
    const uint16_t* V = KV + (size_t)ROWS * HIDDEN;
    const int bh = blockIdx.x;  // b*16+h
    const int sc = blockIdx.y;  // 0..7, 256 rows each
    const int b = bh >> 4, h = bh & 15;
    const int tid = threadIdx.x;
    const size_t base = ((size_t)b * SEQ + sc * 256) * HIDDEN + h * 64;

    __shared__ float kk[16][64];
    __shared__ float vv[16][64];
    float acc[4][4] = {};
    const int i0 = (tid >> 4) * 4, j0 = (tid & 15) * 4;

    for (int batch = 0; batch < 16; ++batch) {
        __syncthreads();
        {
            int t = tid & 127;
            int row = t >> 3, c = t & 7;
            const uint16_t* src =
                (tid < 128 ? K : V) + base + (size_t)(batch * 16 + row) * HIDDEN + c * 8;
            float* dst = (tid < 128 ? &kk[row][c * 8] : &vv[row][c * 8]);
            bf16x8 d = *(const bf16x8*)src;
            for (int e = 0; e < 8; ++e) dst[e] = bf16_to_f32((uint16_t)d[e]);
        }
        __syncthreads();
        for (int r = 0; r < 16; ++r) {
            f32x4 ka = *(const f32x4*)(&kk[r][i0]);
            f32x4 va = *(const f32x4*)(&vv[r][j0]);
            for (int a = 0; a < 4; ++a)
                for (int bb = 0; bb < 4; ++bb)
                    acc[a][bb] += ka[a] * va[bb];
        }
    }
    float* Pp = P + ((size_t)bh * 8 + sc) * 4096;
    for (int a = 0; a < 4; ++a) {
        f32x4 row;
        for (int bb = 0; bb < 4; ++bb) row[bb] = acc[a][bb] * 0.125f;
        *(f32x4*)(&Pp[(i0 + a) * 64 + j0]) = row;
    }
}

// ---------------------------------------------------------------------------
// Kernel 4: fold M into weights — PER BATCH. Sums the 8 kv partials inline.
//   W't[b][n=h*64+j][k=r] = sum_i Wq[r][h*64+i] * M[b*16+h][i][j]   (bf16)
//   b'[b][n]              = sum_i bq[h*64+i]    * M[b*16+h][i][j]   (fp32)
// grid (16 h, 16 rc, 4 b), block 256.
// ---------------------------------------------------------------------------
__global__ __launch_bounds__(256) void wprime_kernel(const float* __restrict__ Wq,
                                                     const float* __restrict__ bq,
                                                     const float* __restrict__ P,
                                                     uint16_t* __restrict__ Wpt,
                                                     float* __restrict__ bp) {
    const int h = blockIdx.x;
    const int r0 = blockIdx.y * 64;
    const int b = blockIdx.z;
    const int tid = threadIdx.x;

    __shared__ float Mh[64][65];
    __shared__ float Wl[64][65];
    const float* Pp = P + ((size_t)(b * 16 + h)) * 8 * 4096;
    for (int it = 0; it < 16; ++it) {
        int e = it * 256 + tid;
        int a = e >> 6, c = e & 63;
        float s = 0.f;
        for (int sc = 0; sc < 8; ++sc) s += Pp[sc * 4096 + e];
        Mh[a][c] = s;
        Wl[a][c] = Wq[(size_t)(r0 + a) * HIDDEN + h * 64 + c];
    }
    __syncthreads();

    const int r = tid & 63;
    const int jbase = tid >> 6; // 0..3
    float acc[16] = {};
    for (int i = 0; i < 64; ++i) {
        float wv = Wl[r][i];
        for (int jj = 0; jj < 16; ++jj)
            acc[jj] += wv * Mh[i][jbase + 4 * jj];
    }
    uint16_t* Wb = Wpt + (size_t)b * HIDDEN * HIDDEN;
    for (int jj = 0; jj < 16; ++jj) {
        int n = h * 64 + jbase + 4 * jj;
        Wb[(size_t)n * HIDDEN + r0 + r] = f32_to_bf16_rne(acc[jj]);
    }

    if (blockIdx.y == 0 && tid < 64) {
        int j = tid;
        float s = 0.f;
        for (int i = 0; i < 64; ++i) s += bq[h * 64 + i] * Mh[i][j];
        bp[b * HIDDEN + h * 64 + j] = s;
    }
}

// ---------------------------------------------------------------------------
// Kernel 5: out = Xq @ W'_b^T + b'_b   (fp32 output to d_out)
//   batch = m0 >> 11 (each 128-row tile lies in one batch).
// ---------------------------------------------------------------------------
__global__ __launch_bounds__(256) void final_gemm(const uint16_t* __restrict__ Xq,
                                                  const uint16_t* __restrict__ Wpt,
                                                  const float* __restrict__ bp,
                                                  float* __restrict__ out) {
    __shared__ uint16_t slds[16384];

    const int tid = threadIdx.x;
    const int lane = tid & 63;
    const int w = tid >> 6;
    const int wm = (w >> 1) * 64;
    const int wn = (w & 1) * 64;
    const int m_lane = lane & 15;
    const int kq = lane >> 4;
    const int m0 = blockIdx.x * 128;
    const int n0 = blockIdx.y * 128;
    const int batch = m0 >> 11;
    const uint16_t* W = Wpt + (size_t)batch * HIDDEN * HIDDEN;
    const float* bias = bp + batch * HIDDEN;

    f32x4 acc[4][4] = {};

    for (int kb = 0; kb < HIDDEN; kb += 64) {
        for (int t = 0; t < 4; ++t) {
            int gbase = (w * 4 + t) * 64;
            int g = gbase + lane;
            int r = g >> 3;
            int c = (g & 7) ^ (r & 7);
            const uint16_t* srcA = Xq + (size_t)(m0 + r) * HIDDEN + kb + c * 8;
            __builtin_amdgcn_global_load_lds(
                (const __attribute__((address_space(1))) uint32_t*)srcA,
                (__attribute__((address_space(3))) uint32_t*)(&slds[gbase * 8]),
                16, 0, 0);
            const uint16_t* srcB = W + (size_t)(n0 + r) * HIDDEN + kb + c * 8;
            __builtin_amdgcn_global_load_lds(
                (const __attribute__((address_space(1))) uint32_t*)srcB,
                (__attribute__((address_space(3))) uint32_t*)(&slds[8192 + gbase * 8]),
                16, 0, 0);
        }
        __syncthreads();
        for (int ks = 0; ks < 2; ++ks) {
            int cbase = ks * 4 + kq;
            bf16x8 af[4], bfr[4];
            for (int i = 0; i < 4; ++i) {
                int r = wm + i * 16 + m_lane;
                int p = cbase ^ (r & 7);
                af[i] = *(const bf16x8*)(&slds[r * 64 + p * 8]);
            }
            for (int j = 0; j < 4; ++j) {
                int nr = wn + j * 16 + m_lane;
                int p = cbase ^ (nr & 7);
                bfr[j] = *(const bf16x8*)(&slds[8192 + nr * 64 + p * 8]);
            }
            for (int i = 0; i < 4; ++i)
                for (int j = 0; j < 4; ++j)
                    acc[i][j] = __builtin_amdgcn_mfma_f32_16x16x32_bf16(
                        af[i], bfr[j], acc[i][j], 0, 0, 0);
        }
        __syncthreads();
    }

    for (int j = 0; j < 4; ++j) {
        int col = n0 + wn + j * 16 + m_lane;
        float bj = bias[col];
        for (int i = 0; i < 4; ++i) {
            int rbase = m0 + wm + i * 16 + kq * 4;
            for (int rg = 0; rg < 4; ++rg)
                out[(size_t)(rbase + rg) * HIDDEN + col] = acc[i][j][rg] + bj;
        }
    }
}

// ---------------------------------------------------------------------------
extern "C" void kernel_launch(void* const* d_in, const int* in_sizes, int n_in,
                              void* d_out, int out_size, void* d_ws, size_t ws_size,
                              hipStream_t stream) {
    const float* Xq = (const float*)d_in[0];
    const float* Xk = (const float*)d_in[1];
    const float* Xv = (const float*)d_in[2];
    const float* Wq = (const float*)d_in[3];
    const float* Bq = (const float*)d_in[4];
    const float* Wk = (const float*)d_in[5];
    const float* Bk = (const float*)d_in[6];
    const float* Wv = (const float*)d_in[7];
    const float* Bv = (const float*)d_in[8];
    float* out = (float*)d_out;

    char* ws = (char*)d_ws;
    uint16_t* Xb = (uint16_t*)ws;                        // 50,331,648 B (Xq,Xk,Xv bf16)
    uint16_t* KV = (uint16_t*)(ws + 50331648);           // 33,554,432 B (K,V bf16)
    uint16_t* Wt = (uint16_t*)(ws + 83886080);           //  4,194,304 B (Wk,Wv bf16 T)
    float* P = (float*)(ws + 88080384);                  //  8,388,608 B (64bh x 8sc x 4096)
    uint16_t* Wpt = (uint16_t*)(ws + 96468992);          //  8,388,608 B (4 x W'_b)
    float* bp = (float*)(ws + 104857600);                //     16,384 B (~100 MB)

    cvt_kernel<<<dim3(3 * 8192), 256, 0, stream>>>(Xq, Xk, Xv, Xb);
    wt_kernel<<<dim3(16, 16, 2), 256, 0, stream>>>(Wk, Wv, Wt);

    const uint16_t* Xkv = Xb + (size_t)ROWS * HIDDEN;
    proj_gemm<<<dim3(64, 8, 2), 256, 0, stream>>>(Xkv, Wt, Bk, Bv, KV);
    kv_kernel<<<dim3(64, 8), 256, 0, stream>>>(KV, P);
    wprime_kernel<<<dim3(16, 16, 4), 256, 0, stream>>>(Wq, Bq, P, Wpt, bp);
    final_gemm<<<dim3(64, 8), 256, 0, stream>>>(Xb, Wpt, bp, out);
}

// Round 9
// 264.533 us; speedup vs baseline: 1.2614x; 1.0202x over previous
//
#include <hip/hip_runtime.h>
#include <stdint.h>

#define HIDDEN 1024
#define HEADS 16
#define HEAD_DIM 64
#define BATCH 4
#define SEQ 2048
#define ROWS (BATCH * SEQ) /* 8192 */

typedef float f32x4 __attribute__((ext_vector_type(4)));
typedef short bf16x8 __attribute__((ext_vector_type(8))); // 8 bf16 = 4 VGPRs

__device__ __forceinline__ uint16_t f32_to_bf16_rne(float f) {
    uint32_t u = __float_as_uint(f);
    uint32_t r = u + 0x7FFFu + ((u >> 16) & 1u);
    return (uint16_t)(r >> 16);
}
__device__ __forceinline__ float bf16_to_f32(uint16_t u) {
    return __uint_as_float(((uint32_t)u) << 16);
}

// ---------------------------------------------------------------------------
// Kernel 0: convert X (q,k,v inputs) fp32 -> bf16, fully coalesced.
// ---------------------------------------------------------------------------
__global__ __launch_bounds__(256) void cvt_kernel(const float* __restrict__ Xq,
                                                  const float* __restrict__ Xk,
                                                  const float* __restrict__ Xv,
                                                  uint16_t* __restrict__ Xb) {
    int z = blockIdx.x >> 13; // 8192 blocks per array
    const float* X = z == 0 ? Xq : (z == 1 ? Xk : Xv);
    uint16_t* out = Xb + (size_t)z * ROWS * HIDDEN;
    size_t i4 = (size_t)(blockIdx.x & 8191) * 256 + threadIdx.x; // float4 index
    float4 f = ((const float4*)X)[i4];
    uint2 pk;
    pk.x = (uint32_t)f32_to_bf16_rne(f.x) | ((uint32_t)f32_to_bf16_rne(f.y) << 16);
    pk.y = (uint32_t)f32_to_bf16_rne(f.z) | ((uint32_t)f32_to_bf16_rne(f.w) << 16);
    ((uint2*)out)[i4] = pk;
}

// ---------------------------------------------------------------------------
// Kernel 1: W[K][N] fp32 -> Wt[N][K] bf16, z in {Wk, Wv} only (Wq stays fp32)
// ---------------------------------------------------------------------------
__global__ __launch_bounds__(256) void wt_kernel(const float* __restrict__ Wk,
                                                 const float* __restrict__ Wv,
                                                 uint16_t* __restrict__ Wt) {
    const float* W = blockIdx.z == 0 ? Wk : Wv;
    uint16_t* out = Wt + (size_t)blockIdx.z * HIDDEN * HIDDEN;
    __shared__ float tile[64][65];
    int k0 = blockIdx.x * 64, n0 = blockIdx.y * 64;
    int r = threadIdx.x >> 6, c = threadIdx.x & 63;
    for (int it = 0; it < 16; ++it) {
        int rr = r + 4 * it;
        tile[rr][c] = W[(size_t)(k0 + rr) * HIDDEN + n0 + c];
    }
    __syncthreads();
    for (int it = 0; it < 16; ++it) {
        int rr = r + 4 * it;
        out[(size_t)(n0 + rr) * HIDDEN + k0 + c] = f32_to_bf16_rne(tile[c][rr]);
    }
}

// ---------------------------------------------------------------------------
// Kernel 2: TRANSPOSED K/V projection: KT[z][n][s_glob] = (X@W^T+b)[s][n].
//   Same verified m97 template with A/B roles swapped: A = Wt rows (n-dim,
//   M=1024 -> 8 tiles), B = Xkv rows (s-dim, N=8192 -> 64 tiles), K=1024.
//   Output row index = n (bias per ROW), col = global s -> coalesced.
//   blockIdx.x = m-tiles (fastest) so the 8 blocks sharing one X s-panel are
//   dispatch-adjacent (L2 temporal locality for the B re-reads).
//   Purpose: K/V are consumed only by kv (reduction over s) -> s-contiguous
//   rows make kv MFMA-able with zero extra transpose kernels.
// ---------------------------------------------------------------------------
__global__ __launch_bounds__(256) void proj_gemm_t(const uint16_t* __restrict__ Xkv,
                                                   const uint16_t* __restrict__ Wt,
                                                   const float* __restrict__ Bk,
                                                   const float* __restrict__ Bv,
                                                   uint16_t* __restrict__ KT) {
    const int z = blockIdx.z; // 0=K, 1=V
    const uint16_t* A = Wt + (size_t)z * HIDDEN * HIDDEN; // rows: n, len 1024
    const uint16_t* B = Xkv + (size_t)z * ROWS * HIDDEN;  // rows: s, len 1024
    const float* bias = z == 0 ? Bk : Bv;
    uint16_t* out = KT + (size_t)z * ROWS * HIDDEN;       // [n][8192]

    __shared__ uint16_t slds[16384]; // A: [0,8192), B: [8192,16384)

    const int tid = threadIdx.x;
    const int lane = tid & 63;
    const int w = tid >> 6;
    const int wm = (w >> 1) * 64;
    const int wn = (w & 1) * 64;
    const int m_lane = lane & 15;
    const int kq = lane >> 4;
    const int m0 = blockIdx.x * 128; // n-dim tile
    const int n0 = blockIdx.y * 128; // s-dim tile

    f32x4 acc[4][4] = {};

    for (int kb = 0; kb < HIDDEN; kb += 64) {
        for (int t = 0; t < 4; ++t) {
            int gbase = (w * 4 + t) * 64;
            int g = gbase + lane;
            int r = g >> 3;
            int c = (g & 7) ^ (r & 7);
            const uint16_t* srcA = A + (size_t)(m0 + r) * HIDDEN + kb + c * 8;
            __builtin_amdgcn_global_load_lds(
                (const __attribute__((address_space(1))) uint32_t*)srcA,
                (__attribute__((address_space(3))) uint32_t*)(&slds[gbase * 8]),
                16, 0, 0);
            const uint16_t* srcB = B + (size_t)(n0 + r) * HIDDEN + kb + c * 8;
            __builtin_amdgcn_global_load_lds(
                (const __attribute__((address_space(1))) uint32_t*)srcB,
                (__attribute__((address_space(3))) uint32_t*)(&slds[8192 + gbase * 8]),
                16, 0, 0);
        }
        __syncthreads();
        for (int ks = 0; ks < 2; ++ks) {
            int cbase = ks * 4 + kq;
            bf16x8 af[4], bfr[4];
            for (int i = 0; i < 4; ++i) {
                int r = wm + i * 16 + m_lane;
                int p = cbase ^ (r & 7);
                af[i] = *(const bf16x8*)(&slds[r * 64 + p * 8]);
            }
            for (int j = 0; j < 4; ++j) {
                int nr = wn + j * 16 + m_lane;
                int p = cbase ^ (nr & 7);
                bfr[j] = *(const bf16x8*)(&slds[8192 + nr * 64 + p * 8]);
            }
            for (int i = 0; i < 4; ++i)
                for (int j = 0; j < 4; ++j)
                    acc[i][j] = __builtin_amdgcn_mfma_f32_16x16x32_bf16(
                        af[i], bfr[j], acc[i][j], 0, 0, 0);
        }
        __syncthreads();
    }

    // C write: row = n (bias per row), col = global s. Same C/D mapping.
    for (int i = 0; i < 4; ++i) {
        for (int rg = 0; rg < 4; ++rg) {
            int row = m0 + wm + i * 16 + kq * 4 + rg;
            float bj = bias[row];
            for (int j = 0; j < 4; ++j) {
                int col = n0 + wn + j * 16 + m_lane;
                out[(size_t)row * ROWS + col] = f32_to_bf16_rne(acc[i][j][rg] + bj);
            }
        }
    }
}

// ---------------------------------------------------------------------------
// Kernel 3: MFMA K^T V.  P[bh][sc][i][j] = 0.125 * sum_{s in chunk}
//   KT[h*64+i][b*2048+sc*256+s] * VT[h*64+j][...]   (both s-contiguous now).
//   Replaces the scalar-VALU outer-product kv_kernel (1.07 GF at v_fmac rate,
//   ~13.6us VALU floor + LDS reads). 64x64 out, 4 waves x (1 A-frag x 4
//   B-frags), BK=64, same chunk-XOR swizzle. grid (64 bh, 8 sc) -> P layout
//   IDENTICAL to the old kv_kernel, wprime unchanged.
// ---------------------------------------------------------------------------
__global__ __launch_bounds__(256) void kv_mfma(const uint16_t* __restrict__ KT,
                                               float* __restrict__ P) {
    const int bh = blockIdx.x;  // b*16+h
    const int sc = blockIdx.y;  // 0..7, 256 s each
    const int b = bh >> 4, h = bh & 15;
    const uint16_t* Kb = KT + (size_t)(h * 64) * ROWS + (size_t)b * SEQ + sc * 256;
    const uint16_t* Vb = Kb + (size_t)HIDDEN * ROWS; // z=1 plane

    __shared__ uint16_t slds[8192]; // A: [0,4096), B: [4096,8192) elems

    const int tid = threadIdx.x;
    const int lane = tid & 63;
    const int w = tid >> 6;      // wave owns output rows w*16..w*16+15
    const int m_lane = lane & 15;
    const int kq = lane >> 4;

    f32x4 acc[4] = {};

    for (int kb = 0; kb < 256; kb += 64) {
        for (int t = 0; t < 2; ++t) {
            int g = t * 256 + tid; // chunk id in [0,512): r = row (64), 8 chunks/row
            int r = g >> 3;
            int c = (g & 7) ^ (r & 7);
            const uint16_t* srcA = Kb + (size_t)r * ROWS + kb + c * 8;
            __builtin_amdgcn_global_load_lds(
                (const __attribute__((address_space(1))) uint32_t*)srcA,
                (__attribute__((address_space(3))) uint32_t*)(&slds[g * 8]),
                16, 0, 0);
            const uint16_t* srcB = Vb + (size_t)r * ROWS + kb + c * 8;
            __builtin_amdgcn_global_load_lds(
                (const __attribute__((address_space(1))) uint32_t*)srcB,
                (__attribute__((address_space(3))) uint32_t*)(&slds[4096 + g * 8]),
                16, 0, 0);
        }
        __syncthreads();
        for (int ks = 0; ks < 2; ++ks) {
            int cbase = ks * 4 + kq;
            int ar = w * 16 + m_lane;
            bf16x8 af = *(const bf16x8*)(&slds[ar * 64 + (cbase ^ (ar & 7)) * 8]);
            for (int j = 0; j < 4; ++j) {
                int br = j * 16 + m_lane;
                bf16x8 bf_ = *(const bf16x8*)(&slds[4096 + br * 64 + (cbase ^ (br & 7)) * 8]);
                acc[j] = __builtin_amdgcn_mfma_f32_16x16x32_bf16(af, bf_, acc[j], 0, 0, 0);
            }
        }
        __syncthreads();
    }

    float* Pp = P + ((size_t)bh * 8 + sc) * 4096;
    for (int j = 0; j < 4; ++j) {
        for (int rg = 0; rg < 4; ++rg) {
            int row = w * 16 + kq * 4 + rg;
            int col = j * 16 + m_lane;
            Pp[row * 64 + col] = acc[j][rg] * 0.125f;
        }
    }
}

// ---------------------------------------------------------------------------
// Kernel 4: fold M into weights — PER BATCH. Sums the 8 kv partials inline.
//   (unchanged; P layout identical to previous rounds)
// ---------------------------------------------------------------------------
__global__ __launch_bounds__(256) void wprime_kernel(const float* __restrict__ Wq,
                                                     const float* __restrict__ bq,
                                                     const float* __restrict__ P,
                                                     uint16_t* __restrict__ Wpt,
                                                     float* __restrict__ bp) {
    const int h = blockIdx.x;
    const int r0 = blockIdx.y * 64;
    const int b = blockIdx.z;
    const int tid = threadIdx.x;

    __shared__ float Mh[64][65];
    __shared__ float Wl[64][65];
    const float* Pp = P + ((size_t)(b * 16 + h)) * 8 * 4096;
    for (int it = 0; it < 16; ++it) {
        int e = it * 256 + tid;
        int a = e >> 6, c = e & 63;
        float s = 0.f;
        for (int sc = 0; sc < 8; ++sc) s += Pp[sc * 4096 + e];
        Mh[a][c] = s;
        Wl[a][c] = Wq[(size_t)(r0 + a) * HIDDEN + h * 64 + c];
    }
    __syncthreads();

    const int r = tid & 63;
    const int jbase = tid >> 6; // 0..3
    float acc[16] = {};
    for (int i = 0; i < 64; ++i) {
        float wv = Wl[r][i];
        for (int jj = 0; jj < 16; ++jj)
            acc[jj] += wv * Mh[i][jbase + 4 * jj];
    }
    uint16_t* Wb = Wpt + (size_t)b * HIDDEN * HIDDEN;
    for (int jj = 0; jj < 16; ++jj) {
        int n = h * 64 + jbase + 4 * jj;
        Wb[(size_t)n * HIDDEN + r0 + r] = f32_to_bf16_rne(acc[jj]);
    }

    if (blockIdx.y == 0 && tid < 64) {
        int j = tid;
        float s = 0.f;
        for (int i = 0; i < 64; ++i) s += bq[h * 64 + i] * Mh[i][j];
        bp[b * HIDDEN + h * 64 + j] = s;
    }
}

// ---------------------------------------------------------------------------
// Kernel 5: out = Xq @ W'_b^T + b'_b   (fp32 output to d_out; unchanged)
// ---------------------------------------------------------------------------
__global__ __launch_bounds__(256) void final_gemm(const uint16_t* __restrict__ Xq,
                                                  const uint16_t* __restrict__ Wpt,
                                                  const float* __restrict__ bp,
                                                  float* __restrict__ out) {
    __shared__ uint16_t slds[16384];

    const int tid = threadIdx.x;
    const int lane = tid & 63;
    const int w = tid >> 6;
    const int wm = (w >> 1) * 64;
    const int wn = (w & 1) * 64;
    const int m_lane = lane & 15;
    const int kq = lane >> 4;
    const int m0 = blockIdx.x * 128;
    const int n0 = blockIdx.y * 128;
    const int batch = m0 >> 11;
    const uint16_t* W = Wpt + (size_t)batch * HIDDEN * HIDDEN;
    const float* bias = bp + batch * HIDDEN;

    f32x4 acc[4][4] = {};

    for (int kb = 0; kb < HIDDEN; kb += 64) {
        for (int t = 0; t < 4; ++t) {
            int gbase = (w * 4 + t) * 64;
            int g = gbase + lane;
            int r = g >> 3;
            int c = (g & 7) ^ (r & 7);
            const uint16_t* srcA = Xq + (size_t)(m0 + r) * HIDDEN + kb + c * 8;
            __builtin_amdgcn_global_load_lds(
                (const __attribute__((address_space(1))) uint32_t*)srcA,
                (__attribute__((address_space(3))) uint32_t*)(&slds[gbase * 8]),
                16, 0, 0);
            const uint16_t* srcB = W + (size_t)(n0 + r) * HIDDEN + kb + c * 8;
            __builtin_amdgcn_global_load_lds(
                (const __attribute__((address_space(1))) uint32_t*)srcB,
                (__attribute__((address_space(3))) uint32_t*)(&slds[8192 + gbase * 8]),
                16, 0, 0);
        }
        __syncthreads();
        for (int ks = 0; ks < 2; ++ks) {
            int cbase = ks * 4 + kq;
            bf16x8 af[4], bfr[4];
            for (int i = 0; i < 4; ++i) {
                int r = wm + i * 16 + m_lane;
                int p = cbase ^ (r & 7);
                af[i] = *(const bf16x8*)(&slds[r * 64 + p * 8]);
            }
            for (int j = 0; j < 4; ++j) {
                int nr = wn + j * 16 + m_lane;
                int p = cbase ^ (nr & 7);
                bfr[j] = *(const bf16x8*)(&slds[8192 + nr * 64 + p * 8]);
            }
            for (int i = 0; i < 4; ++i)
                for (int j = 0; j < 4; ++j)
                    acc[i][j] = __builtin_amdgcn_mfma_f32_16x16x32_bf16(
                        af[i], bfr[j], acc[i][j], 0, 0, 0);
        }
        __syncthreads();
    }

    for (int j = 0; j < 4; ++j) {
        int col = n0 + wn + j * 16 + m_lane;
        float bj = bias[col];
        for (int i = 0; i < 4; ++i) {
            int rbase = m0 + wm + i * 16 + kq * 4;
            for (int rg = 0; rg < 4; ++rg)
                out[(size_t)(rbase + rg) * HIDDEN + col] = acc[i][j][rg] + bj;
        }
    }
}

// ---------------------------------------------------------------------------
extern "C" void kernel_launch(void* const* d_in, const int* in_sizes, int n_in,
                              void* d_out, int out_size, void* d_ws, size_t ws_size,
                              hipStream_t stream) {
    const float* Xq = (const float*)d_in[0];
    const float* Xk = (const float*)d_in[1];
    const float* Xv = (const float*)d_in[2];
    const float* Wq = (const float*)d_in[3];
    const float* Bq = (const float*)d_in[4];
    const float* Wk = (const float*)d_in[5];
    const float* Bk = (const float*)d_in[6];
    const float* Wv = (const float*)d_in[7];
    const float* Bv = (const float*)d_in[8];
    float* out = (float*)d_out;

    char* ws = (char*)d_ws;
    uint16_t* Xb = (uint16_t*)ws;                        // 50,331,648 B (Xq,Xk,Xv bf16)
    uint16_t* KT = (uint16_t*)(ws + 50331648);           // 33,554,432 B (K^T,V^T bf16)
    uint16_t* Wt = (uint16_t*)(ws + 83886080);           //  4,194,304 B (Wk,Wv bf16 T)
    float* P = (float*)(ws + 88080384);                  //  8,388,608 B (64bh x 8sc x 4096)
    uint16_t* Wpt = (uint16_t*)(ws + 96468992);          //  8,388,608 B (4 x W'_b)
    float* bp = (float*)(ws + 104857600);                //     16,384 B (~100 MB)

    cvt_kernel<<<dim3(3 * 8192), 256, 0, stream>>>(Xq, Xk, Xv, Xb);
    wt_kernel<<<dim3(16, 16, 2), 256, 0, stream>>>(Wk, Wv, Wt);

    const uint16_t* Xkv = Xb + (size_t)ROWS * HIDDEN;
    // Transposed projection: KT[z][n][8192]. x = n-tiles (8, fastest) so the
    // 8 blocks sharing an X s-panel are dispatch-adjacent.
    proj_gemm_t<<<dim3(8, 64, 2), 256, 0, stream>>>(Xkv, Wt, Bk, Bv, KT);
    kv_mfma<<<dim3(64, 8), 256, 0, stream>>>(KT, P);
    wprime_kernel<<<dim3(16, 16, 4), 256, 0, stream>>>(Wq, Bq, P, Wpt, bp);
    final_gemm<<<dim3(64, 8), 256, 0, stream>>>(Xb, Wpt, bp, out);
}

// Round 10
// 258.861 us; speedup vs baseline: 1.2890x; 1.0219x over previous
//
#include <hip/hip_runtime.h>
#include <stdint.h>

#define HIDDEN 1024
#define HEADS 16
#define HEAD_DIM 64
#define BATCH 4
#define SEQ 2048
#define ROWS (BATCH * SEQ) /* 8192 */

typedef float f32x4 __attribute__((ext_vector_type(4)));
typedef short bf16x8 __attribute__((ext_vector_type(8))); // 8 bf16 = 4 VGPRs

__device__ __forceinline__ uint16_t f32_to_bf16_rne(float f) {
    uint32_t u = __float_as_uint(f);
    uint32_t r = u + 0x7FFFu + ((u >> 16) & 1u);
    return (uint16_t)(r >> 16);
}
__device__ __forceinline__ float bf16_to_f32(uint16_t u) {
    return __uint_as_float(((uint32_t)u) << 16);
}

// ---------------------------------------------------------------------------
// Kernel 0: convert X (q,k,v inputs) fp32 -> bf16, fully coalesced.
// ---------------------------------------------------------------------------
__global__ __launch_bounds__(256) void cvt_kernel(const float* __restrict__ Xq,
                                                  const float* __restrict__ Xk,
                                                  const float* __restrict__ Xv,
                                                  uint16_t* __restrict__ Xb) {
    int z = blockIdx.x >> 13; // 8192 blocks per array
    const float* X = z == 0 ? Xq : (z == 1 ? Xk : Xv);
    uint16_t* out = Xb + (size_t)z * ROWS * HIDDEN;
    size_t i4 = (size_t)(blockIdx.x & 8191) * 256 + threadIdx.x; // float4 index
    float4 f = ((const float4*)X)[i4];
    uint2 pk;
    pk.x = (uint32_t)f32_to_bf16_rne(f.x) | ((uint32_t)f32_to_bf16_rne(f.y) << 16);
    pk.y = (uint32_t)f32_to_bf16_rne(f.z) | ((uint32_t)f32_to_bf16_rne(f.w) << 16);
    ((uint2*)out)[i4] = pk;
}

// ---------------------------------------------------------------------------
// Kernel 1: W[K][N] fp32 -> Wt[N][K] bf16, z in {Wk, Wv} only (Wq stays fp32)
// ---------------------------------------------------------------------------
__global__ __launch_bounds__(256) void wt_kernel(const float* __restrict__ Wk,
                                                 const float* __restrict__ Wv,
                                                 uint16_t* __restrict__ Wt) {
    const float* W = blockIdx.z == 0 ? Wk : Wv;
    uint16_t* out = Wt + (size_t)blockIdx.z * HIDDEN * HIDDEN;
    __shared__ float tile[64][65];
    int k0 = blockIdx.x * 64, n0 = blockIdx.y * 64;
    int r = threadIdx.x >> 6, c = threadIdx.x & 63;
    for (int it = 0; it < 16; ++it) {
        int rr = r + 4 * it;
        tile[rr][c] = W[(size_t)(k0 + rr) * HIDDEN + n0 + c];
    }
    __syncthreads();
    for (int it = 0; it < 16; ++it) {
        int rr = r + 4 * it;
        out[(size_t)(n0 + rr) * HIDDEN + k0 + c] = f32_to_bf16_rne(tile[c][rr]);
    }
}

// ---------------------------------------------------------------------------
// Kernel 2: TRANSPOSED K/V projection: KT[z][n][s_glob] = (X@W^T+b)[s][n].
//   m97 template, A = Wt rows (n), B = Xkv rows (s), K=1024.
//   XCD-AWARE 1-D GRID (R9 fix): R9's x-fastest order put the 8 m-tiles
//   sharing one X s-panel on 8 DIFFERENT XCDs (private L2s) -> X fetched 8x
//   (FETCH 133 MB vs 36 compulsory). Remap so all 8 m-tiles of a panel have
//   linear idx == y (mod 8) -> same XCD -> panel fetched once per XCD:
//     i = (y&7) + 8*(m + 8*((y>>3) + 8*z)),  bijective on [0,1024).
// ---------------------------------------------------------------------------
__global__ __launch_bounds__(256) void proj_gemm_t(const uint16_t* __restrict__ Xkv,
                                                   const uint16_t* __restrict__ Wt,
                                                   const float* __restrict__ Bk,
                                                   const float* __restrict__ Bv,
                                                   uint16_t* __restrict__ KT) {
    // decode XCD-swizzled linear block id
    const int i = blockIdx.x;
    const int xcd = i & 7;
    const int slot = i >> 3;
    const int mt = slot & 7;          // m-tile (n-dim), 0..7
    const int yhi = (slot >> 3) & 7;  // upper 3 bits of s-tile
    const int z = slot >> 6;          // 0=K, 1=V
    const int yt = xcd + 8 * yhi;     // s-tile, 0..63

    const uint16_t* A = Wt + (size_t)z * HIDDEN * HIDDEN; // rows: n, len 1024
    const uint16_t* B = Xkv + (size_t)z * ROWS * HIDDEN;  // rows: s, len 1024
    const float* bias = z == 0 ? Bk : Bv;
    uint16_t* out = KT + (size_t)z * ROWS * HIDDEN;       // [n][8192]

    __shared__ uint16_t slds[16384]; // A: [0,8192), B: [8192,16384)

    const int tid = threadIdx.x;
    const int lane = tid & 63;
    const int w = tid >> 6;
    const int wm = (w >> 1) * 64;
    const int wn = (w & 1) * 64;
    const int m_lane = lane & 15;
    const int kq = lane >> 4;
    const int m0 = mt * 128; // n-dim tile
    const int n0 = yt * 128; // s-dim tile

    f32x4 acc[4][4] = {};

    for (int kb = 0; kb < HIDDEN; kb += 64) {
        for (int t = 0; t < 4; ++t) {
            int gbase = (w * 4 + t) * 64;
            int g = gbase + lane;
            int r = g >> 3;
            int c = (g & 7) ^ (r & 7);
            const uint16_t* srcA = A + (size_t)(m0 + r) * HIDDEN + kb + c * 8;
            __builtin_amdgcn_global_load_lds(
                (const __attribute__((address_space(1))) uint32_t*)srcA,
                (__attribute__((address_space(3))) uint32_t*)(&slds[gbase * 8]),
                16, 0, 0);
            const uint16_t* srcB = B + (size_t)(n0 + r) * HIDDEN + kb + c * 8;
            __builtin_amdgcn_global_load_lds(
                (const __attribute__((address_space(1))) uint32_t*)srcB,
                (__attribute__((address_space(3))) uint32_t*)(&slds[8192 + gbase * 8]),
                16, 0, 0);
        }
        __syncthreads();
        for (int ks = 0; ks < 2; ++ks) {
            int cbase = ks * 4 + kq;
            bf16x8 af[4], bfr[4];
            for (int i2 = 0; i2 < 4; ++i2) {
                int r = wm + i2 * 16 + m_lane;
                int p = cbase ^ (r & 7);
                af[i2] = *(const bf16x8*)(&slds[r * 64 + p * 8]);
            }
            for (int j = 0; j < 4; ++j) {
                int nr = wn + j * 16 + m_lane;
                int p = cbase ^ (nr & 7);
                bfr[j] = *(const bf16x8*)(&slds[8192 + nr * 64 + p * 8]);
            }
            for (int i2 = 0; i2 < 4; ++i2)
                for (int j = 0; j < 4; ++j)
                    acc[i2][j] = __builtin_amdgcn_mfma_f32_16x16x32_bf16(
                        af[i2], bfr[j], acc[i2][j], 0, 0, 0);
        }
        __syncthreads();
    }

    // C write: row = n (bias per row), col = global s. Same C/D mapping.
    for (int i2 = 0; i2 < 4; ++i2) {
        for (int rg = 0; rg < 4; ++rg) {
            int row = m0 + wm + i2 * 16 + kq * 4 + rg;
            float bj = bias[row];
            for (int j = 0; j < 4; ++j) {
                int col = n0 + wn + j * 16 + m_lane;
                out[(size_t)row * ROWS + col] = f32_to_bf16_rne(acc[i2][j][rg] + bj);
            }
        }
    }
}

// ---------------------------------------------------------------------------
// Kernel 3: MFMA K^T V.  P[bh][sc][i][j] = 0.125 * sum_{s in chunk}
//   KT[h*64+i][b*2048+sc*256+s] * VT[h*64+j][...]   (both s-contiguous).
//   (Verified R9: replaced scalar-VALU kv_kernel, total -5.3 us.)
// ---------------------------------------------------------------------------
__global__ __launch_bounds__(256) void kv_mfma(const uint16_t* __restrict__ KT,
                                               float* __restrict__ P) {
    const int bh = blockIdx.x;  // b*16+h
    const int sc = blockIdx.y;  // 0..7, 256 s each
    const int b = bh >> 4, h = bh & 15;
    const uint16_t* Kb = KT + (size_t)(h * 64) * ROWS + (size_t)b * SEQ + sc * 256;
    const uint16_t* Vb = Kb + (size_t)HIDDEN * ROWS; // z=1 plane

    __shared__ uint16_t slds[8192]; // A: [0,4096), B: [4096,8192) elems

    const int tid = threadIdx.x;
    const int lane = tid & 63;
    const int w = tid >> 6;      // wave owns output rows w*16..w*16+15
    const int m_lane = lane & 15;
    const int kq = lane >> 4;

    f32x4 acc[4] = {};

    for (int kb = 0; kb < 256; kb += 64) {
        for (int t = 0; t < 2; ++t) {
            int g = t * 256 + tid; // chunk id in [0,512): r = row (64), 8 chunks/row
            int r = g >> 3;
            int c = (g & 7) ^ (r & 7);
            const uint16_t* srcA = Kb + (size_t)r * ROWS + kb + c * 8;
            __builtin_amdgcn_global_load_lds(
                (const __attribute__((address_space(1))) uint32_t*)srcA,
                (__attribute__((address_space(3))) uint32_t*)(&slds[g * 8]),
                16, 0, 0);
            const uint16_t* srcB = Vb + (size_t)r * ROWS + kb + c * 8;
            __builtin_amdgcn_global_load_lds(
                (const __attribute__((address_space(1))) uint32_t*)srcB,
                (__attribute__((address_space(3))) uint32_t*)(&slds[4096 + g * 8]),
                16, 0, 0);
        }
        __syncthreads();
        for (int ks = 0; ks < 2; ++ks) {
            int cbase = ks * 4 + kq;
            int ar = w * 16 + m_lane;
            bf16x8 af = *(const bf16x8*)(&slds[ar * 64 + (cbase ^ (ar & 7)) * 8]);
            for (int j = 0; j < 4; ++j) {
                int br = j * 16 + m_lane;
                bf16x8 bf_ = *(const bf16x8*)(&slds[4096 + br * 64 + (cbase ^ (br & 7)) * 8]);
                acc[j] = __builtin_amdgcn_mfma_f32_16x16x32_bf16(af, bf_, acc[j], 0, 0, 0);
            }
        }
        __syncthreads();
    }

    float* Pp = P + ((size_t)bh * 8 + sc) * 4096;
    for (int j = 0; j < 4; ++j) {
        for (int rg = 0; rg < 4; ++rg) {
            int row = w * 16 + kq * 4 + rg;
            int col = j * 16 + m_lane;
            Pp[row * 64 + col] = acc[j][rg] * 0.125f;
        }
    }
}

// ---------------------------------------------------------------------------
// Kernel 4: fold M into weights — PER BATCH. Sums the 8 kv partials inline.
// ---------------------------------------------------------------------------
__global__ __launch_bounds__(256) void wprime_kernel(const float* __restrict__ Wq,
                                                     const float* __restrict__ bq,
                                                     const float* __restrict__ P,
                                                     uint16_t* __restrict__ Wpt,
                                                     float* __restrict__ bp) {
    const int h = blockIdx.x;
    const int r0 = blockIdx.y * 64;
    const int b = blockIdx.z;
    const int tid = threadIdx.x;

    __shared__ float Mh[64][65];
    __shared__ float Wl[64][65];
    const float* Pp = P + ((size_t)(b * 16 + h)) * 8 * 4096;
    for (int it = 0; it < 16; ++it) {
        int e = it * 256 + tid;
        int a = e >> 6, c = e & 63;
        float s = 0.f;
        for (int sc = 0; sc < 8; ++sc) s += Pp[sc * 4096 + e];
        Mh[a][c] = s;
        Wl[a][c] = Wq[(size_t)(r0 + a) * HIDDEN + h * 64 + c];
    }
    __syncthreads();

    const int r = tid & 63;
    const int jbase = tid >> 6; // 0..3
    float acc[16] = {};
    for (int i = 0; i < 64; ++i) {
        float wv = Wl[r][i];
        for (int jj = 0; jj < 16; ++jj)
            acc[jj] += wv * Mh[i][jbase + 4 * jj];
    }
    uint16_t* Wb = Wpt + (size_t)b * HIDDEN * HIDDEN;
    for (int jj = 0; jj < 16; ++jj) {
        int n = h * 64 + jbase + 4 * jj;
        Wb[(size_t)n * HIDDEN + r0 + r] = f32_to_bf16_rne(acc[jj]);
    }

    if (blockIdx.y == 0 && tid < 64) {
        int j = tid;
        float s = 0.f;
        for (int i = 0; i < 64; ++i) s += bq[h * 64 + i] * Mh[i][j];
        bp[b * HIDDEN + h * 64 + j] = s;
    }
}

// ---------------------------------------------------------------------------
// Kernel 5: out = Xq @ W'_b^T + b'_b   (fp32 output to d_out)
// ---------------------------------------------------------------------------
__global__ __launch_bounds__(256) void final_gemm(const uint16_t* __restrict__ Xq,
                                                  const uint16_t* __restrict__ Wpt,
                                                  const float* __restrict__ bp,
                                                  float* __restrict__ out) {
    __shared__ uint16_t slds[16384];

    const int tid = threadIdx.x;
    const int lane = tid & 63;
    const int w = tid >> 6;
    const int wm = (w >> 1) * 64;
    const int wn = (w & 1) * 64;
    const int m_lane = lane & 15;
    const int kq = lane >> 4;
    const int m0 = blockIdx.x * 128;
    const int n0 = blockIdx.y * 128;
    const int batch = m0 >> 11;
    const uint16_t* W = Wpt + (size_t)batch * HIDDEN * HIDDEN;
    const float* bias = bp + batch * HIDDEN;

    f32x4 acc[4][4] = {};

    for (int kb = 0; kb < HIDDEN; kb += 64) {
        for (int t = 0; t < 4; ++t) {
            int gbase = (w * 4 + t) * 64;
            int g = gbase + lane;
            int r = g >> 3;
            int c = (g & 7) ^ (r & 7);
            const uint16_t* srcA = Xq + (size_t)(m0 + r) * HIDDEN + kb + c * 8;
            __builtin_amdgcn_global_load_lds(
                (const __attribute__((address_space(1))) uint32_t*)srcA,
                (__attribute__((address_space(3))) uint32_t*)(&slds[gbase * 8]),
                16, 0, 0);
            const uint16_t* srcB = W + (size_t)(n0 + r) * HIDDEN + kb + c * 8;
            __builtin_amdgcn_global_load_lds(
                (const __attribute__((address_space(1))) uint32_t*)srcB,
                (__attribute__((address_space(3))) uint32_t*)(&slds[8192 + gbase * 8]),
                16, 0, 0);
        }
        __syncthreads();
        for (int ks = 0; ks < 2; ++ks) {
            int cbase = ks * 4 + kq;
            bf16x8 af[4], bfr[4];
            for (int i = 0; i < 4; ++i) {
                int r = wm + i * 16 + m_lane;
                int p = cbase ^ (r & 7);
                af[i] = *(const bf16x8*)(&slds[r * 64 + p * 8]);
            }
            for (int j = 0; j < 4; ++j) {
                int nr = wn + j * 16 + m_lane;
                int p = cbase ^ (nr & 7);
                bfr[j] = *(const bf16x8*)(&slds[8192 + nr * 64 + p * 8]);
            }
            for (int i = 0; i < 4; ++i)
                for (int j = 0; j < 4; ++j)
                    acc[i][j] = __builtin_amdgcn_mfma_f32_16x16x32_bf16(
                        af[i], bfr[j], acc[i][j], 0, 0, 0);
        }
        __syncthreads();
    }

    for (int j = 0; j < 4; ++j) {
        int col = n0 + wn + j * 16 + m_lane;
        float bj = bias[col];
        for (int i = 0; i < 4; ++i) {
            int rbase = m0 + wm + i * 16 + kq * 4;
            for (int rg = 0; rg < 4; ++rg)
                out[(size_t)(rbase + rg) * HIDDEN + col] = acc[i][j][rg] + bj;
        }
    }
}

// ---------------------------------------------------------------------------
extern "C" void kernel_launch(void* const* d_in, const int* in_sizes, int n_in,
                              void* d_out, int out_size, void* d_ws, size_t ws_size,
                              hipStream_t stream) {
    const float* Xq = (const float*)d_in[0];
    const float* Xk = (const float*)d_in[1];
    const float* Xv = (const float*)d_in[2];
    const float* Wq = (const float*)d_in[3];
    const float* Bq = (const float*)d_in[4];
    const float* Wk = (const float*)d_in[5];
    const float* Bk = (const float*)d_in[6];
    const float* Wv = (const float*)d_in[7];
    const float* Bv = (const float*)d_in[8];
    float* out = (float*)d_out;

    char* ws = (char*)d_ws;
    uint16_t* Xb = (uint16_t*)ws;                        // 50,331,648 B (Xq,Xk,Xv bf16)
    uint16_t* KT = (uint16_t*)(ws + 50331648);           // 33,554,432 B (K^T,V^T bf16)
    uint16_t* Wt = (uint16_t*)(ws + 83886080);           //  4,194,304 B (Wk,Wv bf16 T)
    float* P = (float*)(ws + 88080384);                  //  8,388,608 B (64bh x 8sc x 4096)
    uint16_t* Wpt = (uint16_t*)(ws + 96468992);          //  8,388,608 B (4 x W'_b)
    float* bp = (float*)(ws + 104857600);                //     16,384 B (~100 MB)

    cvt_kernel<<<dim3(3 * 8192), 256, 0, stream>>>(Xq, Xk, Xv, Xb);
    wt_kernel<<<dim3(16, 16, 2), 256, 0, stream>>>(Wk, Wv, Wt);

    const uint16_t* Xkv = Xb + (size_t)ROWS * HIDDEN;
    // XCD-swizzled 1-D grid: 1024 blocks, i = (y&7) + 8*(m + 8*((y>>3) + 8*z)).
    proj_gemm_t<<<dim3(1024), 256, 0, stream>>>(Xkv, Wt, Bk, Bv, KT);
    kv_mfma<<<dim3(64, 8), 256, 0, stream>>>(KT, P);
    wprime_kernel<<<dim3(16, 16, 4), 256, 0, stream>>>(Wq, Bq, P, Wpt, bp);
    final_gemm<<<dim3(64, 8), 256, 0, stream>>>(Xb, Wpt, bp, out);
}